// Round 3
// baseline (358.572 us; speedup 1.0000x reference)
//
#include <hip/hip_runtime.h>
#include <hip/hip_bf16.h>
#include <math.h>

#define H 256
#define NR 14000
#define MR 100000
#define K1C 16
#define K2C 32
#define KT 48
#define CC 7
#define EPSF 1e-8f
#define GP 448
#define CH2 32            // GP*CH2 = 14336 >= NR

typedef __attribute__((ext_vector_type(8))) unsigned short ushort8_t;

__device__ __forceinline__ float rdlane(float v, int l) {
    return __int_as_float(__builtin_amdgcn_readlane(__float_as_int(v), l));
}

__device__ __forceinline__ float dot4(const float4 a, const float4 b) {
    return a.x * b.x + a.y * b.y + a.z * b.z + a.w * b.w;
}

__device__ __forceinline__ unsigned short f2bf(float x) {
    __hip_bfloat16 h = __float2bfloat16(x);   // RTNE
    return *(unsigned short*)&h;
}

// ---------------- Kernel E: fp32 table -> bf16 table ------------------------
__global__ __launch_bounds__(256) void kE(const float* __restrict__ src,
                                          unsigned short* __restrict__ dst) {
    const size_t base = ((size_t)blockIdx.x * 256 + threadIdx.x) * 8;
    const float4 a = *(const float4*)(src + base);
    const float4 b = *(const float4*)(src + base + 4);
    ushort8_t o;
    o[0] = f2bf(a.x); o[1] = f2bf(a.y); o[2] = f2bf(a.z); o[3] = f2bf(a.w);
    o[4] = f2bf(b.x); o[5] = f2bf(b.y); o[6] = f2bf(b.z); o[7] = f2bf(b.w);
    *(ushort8_t*)(dst + base) = o;
}

// ---------------- Kernel A3: gather + cos-softmax + adapter (fused) ---------
// One wave per n. Gather phase as round 2 (4 groups x 16 lanes, bf16 rows,
// fixed-shift softmax). After group-merge every lane holds the full 256-dim
// input row (lane l=lane&15 owns h in [16l,16l+16), replicated over groups).
// Adapter fused in-register:
//   matmul1: lane = hidden unit b; in[h] broadcast via v_readlane (const lane
//            index after unroll), W1 column loads coalesced from L2.
//   matmul2: group g handles b in [16g,16g+16) via bpermute __shfl of hid;
//            partials merged with 2 shuffle-xor levels -> output stays in the
//            gather's h-ownership layout; g==0 writes rawret.
__global__ __launch_bounds__(256) void kA3(
    const float* __restrict__ embeds, const unsigned short* __restrict__ ebf,
    const float* __restrict__ w_self, const float* __restrict__ w_n,
    const float* __restrict__ w_n2, const int* __restrict__ idx,
    const int* __restrict__ nbr1, const int* __restrict__ nbr2,
    const float* __restrict__ W1, const float* __restrict__ b1,
    const float* __restrict__ W2, const float* __restrict__ b2,
    float* __restrict__ rawret)
{
    const int tid = threadIdx.x;
    const int wv = tid >> 6, lane = tid & 63;
    const int n = blockIdx.x * 4 + wv;
    const int g = lane >> 4, l = lane & 15;
    const int hb = l * 16;

    float ce[16], wn[16], wn2[16];
    float na2 = 0.f;
    const int cidx = idx[n];
    const float* crow = embeds + (size_t)cidx * H + hb;
#pragma unroll
    for (int j = 0; j < 4; ++j) {
        const float4 wsv  = *(const float4*)(w_self + hb + 4 * j);
        const float4 wnv  = *(const float4*)(w_n    + hb + 4 * j);
        const float4 wn2v = *(const float4*)(w_n2   + hb + 4 * j);
        const float4 cv   = *(const float4*)(crow + 4 * j);
        wn[4*j+0] = wnv.x;  wn[4*j+1] = wnv.y;  wn[4*j+2] = wnv.z;  wn[4*j+3] = wnv.w;
        wn2[4*j+0] = wn2v.x; wn2[4*j+1] = wn2v.y; wn2[4*j+2] = wn2v.z; wn2[4*j+3] = wn2v.w;
        ce[4*j+0] = wsv.x * cv.x; ce[4*j+1] = wsv.y * cv.y;
        ce[4*j+2] = wsv.z * cv.z; ce[4*j+3] = wsv.w * cv.w;
        na2 += ce[4*j+0]*ce[4*j+0] + ce[4*j+1]*ce[4*j+1]
             + ce[4*j+2]*ce[4*j+2] + ce[4*j+3]*ce[4*j+3];
    }
#pragma unroll
    for (int m = 1; m <= 8; m <<= 1) na2 += __shfl_xor(na2, m);
    const float na = fmaxf(sqrtf(na2), EPSF);

    int ridx = 0;
    if (lane < K1C) ridx = nbr1[n * K1C + lane];
    else if (lane < KT) ridx = nbr2[n * K2C + (lane - K1C)];

    float acc[16];
#pragma unroll
    for (int i = 0; i < 16; ++i) acc[i] = 0.f;
    float lsum = 0.f;

#pragma unroll
    for (int kk = 0; kk < 12; ++kk) {
        const int row = __shfl(ridx, kk * 4 + g);
        const unsigned short* rp = ebf + (size_t)row * H + hb;
        const ushort8_t e0 = *(const ushort8_t*)(rp);
        const ushort8_t e1 = *(const ushort8_t*)(rp + 8);
        float nb[16];
#pragma unroll
        for (int i = 0; i < 8; ++i) {
            nb[i]     = __uint_as_float((unsigned)e0[i] << 16);
            nb[8 + i] = __uint_as_float((unsigned)e1[i] << 16);
        }
        float num = 0.f, nn = 0.f;
#pragma unroll
        for (int i = 0; i < 16; ++i) {
            const float w = (kk < 4) ? wn[i] : wn2[i];  // compile-time after unroll
            nb[i] *= w;
            num += ce[i] * nb[i];
            nn  += nb[i] * nb[i];
        }
#pragma unroll
        for (int m = 1; m <= 8; m <<= 1) {
            num += __shfl_xor(num, m);
            nn  += __shfl_xor(nn, m);
        }
        const float nbn = fmaxf(sqrtf(nn), EPSF);
        const float e = __expf(num / (nbn * na) - 1.0f);   // sim <= 1
        lsum += e;
#pragma unroll
        for (int i = 0; i < 16; ++i) acc[i] += e * nb[i];
    }
    // merge the 4 groups -> every lane holds the full weighted sum for its l
#pragma unroll
    for (int m = 16; m <= 32; m <<= 1) {
        lsum += __shfl_xor(lsum, m);
#pragma unroll
        for (int i = 0; i < 16; ++i) acc[i] += __shfl_xor(acc[i], m);
    }
    const float rl = 1.0f / lsum;
    float inv[16];
#pragma unroll
    for (int i = 0; i < 16; ++i) inv[i] = acc[i] * rl + ce[i];  // adapter input

    // ---- matmul1: hid[lane] = b1[lane] + sum_h in[h] * W1[h][lane] ----
    float hid = b1[lane];
    const float* w1p = W1 + lane;
#pragma unroll
    for (int l2 = 0; l2 < 16; ++l2) {
#pragma unroll
        for (int i = 0; i < 16; ++i) {
            const int h = 16 * l2 + i;
            hid = fmaf(rdlane(inv[i], l2), w1p[h * 64], hid);
        }
    }
    hid = hid > 0.f ? hid : (__expf(hid) - 1.0f);   // elu

    // ---- matmul2: group g covers b in [16g,16g+16); lane l owns h block ----
    float p[16];
#pragma unroll
    for (int i = 0; i < 16; ++i) p[i] = 0.f;
    const int gb = lane & 48;   // 16*g
#pragma unroll
    for (int t = 0; t < 16; ++t) {
        const float hv = __shfl(hid, gb + t);
        const float* w2p = W2 + (size_t)(gb + t) * H + hb;
#pragma unroll
        for (int j = 0; j < 4; ++j) {
            const float4 w2v = *(const float4*)(w2p + 4 * j);
            p[4*j+0] = fmaf(hv, w2v.x, p[4*j+0]);
            p[4*j+1] = fmaf(hv, w2v.y, p[4*j+1]);
            p[4*j+2] = fmaf(hv, w2v.z, p[4*j+2]);
            p[4*j+3] = fmaf(hv, w2v.w, p[4*j+3]);
        }
    }
#pragma unroll
    for (int m = 16; m <= 32; m <<= 1) {
#pragma unroll
        for (int i = 0; i < 16; ++i) p[i] += __shfl_xor(p[i], m);
    }

    if (g == 0) {
        float* op = rawret + (size_t)n * H + hb;
#pragma unroll
        for (int j = 0; j < 4; ++j) {
            const float4 b2v = *(const float4*)(b2 + hb + 4 * j);
            float4 ov;
            ov.x = p[4*j+0] + b2v.x + ce[4*j+0];
            ov.y = p[4*j+1] + b2v.y + ce[4*j+1];
            ov.z = p[4*j+2] + b2v.z + ce[4*j+2];
            ov.w = p[4*j+3] + b2v.w + ce[4*j+3];
            *(float4*)(op + 4 * j) = ov;
        }
    }
}

// ---------------- Kernel C1: per-chunk per-class partial sums ---------------
// 448 blocks x 32 rows: 1.75 blocks/CU, 4-deep load pipelining.
__global__ __launch_bounds__(256) void kC1(
    const float* __restrict__ rawret, const int* __restrict__ labels,
    float* __restrict__ partial)
{
    const int t = threadIdx.x, j = blockIdx.x;
    const int nlo = j * CH2;
    const int nhi = min(nlo + CH2, NR);
    float acc[CC];
#pragma unroll
    for (int c = 0; c < CC; ++c) acc[c] = 0.f;
    for (int n = nlo; n < nhi; n += 4) {      // bounds are multiples of 4
        int lab[4]; float v[4];
#pragma unroll
        for (int u = 0; u < 4; ++u) {
            lab[u] = labels[n + u];
            v[u] = rawret[(size_t)(n + u) * H + t];
        }
#pragma unroll
        for (int u = 0; u < 4; ++u)
#pragma unroll
            for (int c = 0; c < CC; ++c) acc[c] += (lab[u] == c) ? v[u] : 0.f;
    }
#pragma unroll
    for (int c = 0; c < CC; ++c) partial[(size_t)(j * CC + c) * H + t] = acc[c];
}

// ---------------- Kernel C2: finalize class means + norms -------------------
__global__ __launch_bounds__(256) void kC2(
    const float* __restrict__ partial, float* __restrict__ ave,
    float* __restrict__ anorm)
{
    const int c = blockIdx.x, t = threadIdx.x;
    float s = 0.f;
#pragma unroll 8
    for (int j = 0; j < GP; ++j) s += partial[(size_t)(j * CC + c) * H + t];
    const float a = s * (1.0f / 2000.0f);   // per_class = N // C
    ave[c * H + t] = a;
    __shared__ float red[256];
    red[t] = a * a;
    __syncthreads();
    for (int m = 128; m > 0; m >>= 1) {
        if (t < m) red[t] += red[t + m];
        __syncthreads();
    }
    if (t == 0) anorm[c] = fmaxf(sqrtf(red[0]), EPSF);
}

// ---------------- Kernel D: class-cosine softmax -> out [N,7] ---------------
__global__ __launch_bounds__(256) void kD(
    const float* __restrict__ rawret, const float* __restrict__ ave,
    const float* __restrict__ anorm, float* __restrict__ out)
{
    const int tid = threadIdx.x;
    const int wv = tid >> 6, lane = tid & 63;
    const int n = blockIdx.x * 4 + wv;
    const float4 r4 = *(const float4*)(rawret + (size_t)n * H + 4 * lane);
    float nr2 = dot4(r4, r4);
#pragma unroll
    for (int m = 1; m <= 32; m <<= 1) nr2 += __shfl_xor(nr2, m);
    const float rn = fmaxf(sqrtf(nr2), EPSF);

    float e[CC];
    float s = 0.f;
#pragma unroll
    for (int c = 0; c < CC; ++c) {
        const float4 a4 = *(const float4*)(ave + c * H + 4 * lane);
        float d = dot4(r4, a4);
#pragma unroll
        for (int m = 1; m <= 32; m <<= 1) d += __shfl_xor(d, m);
        const float sim = d / (rn * anorm[c]);
        e[c] = __expf(sim - 1.0f);
        s += e[c];
    }
    const float rs = 1.0f / s;
    if (lane < CC) {
        float v = e[0];
#pragma unroll
        for (int c = 1; c < CC; ++c) v = (lane == c) ? e[c] : v;
        out[(size_t)n * CC + lane] = v * rs;
    }
}

extern "C" void kernel_launch(void* const* d_in, const int* in_sizes, int n_in,
                              void* d_out, int out_size, void* d_ws, size_t ws_size,
                              hipStream_t stream) {
    const float* embeds = (const float*)d_in[0];
    const float* w_self = (const float*)d_in[1];
    const float* w_n    = (const float*)d_in[2];
    const float* w_n2   = (const float*)d_in[3];
    const float* W1     = (const float*)d_in[4];
    const float* b1     = (const float*)d_in[5];
    const float* W2     = (const float*)d_in[6];
    const float* b2     = (const float*)d_in[7];
    const int* idx      = (const int*)d_in[8];
    const int* nbr1     = (const int*)d_in[9];
    const int* nbr2     = (const int*)d_in[10];
    const int* labels   = (const int*)d_in[11];
    float* out = (float*)d_out;

    float* rawret  = (float*)d_ws;                       // N*H
    float* partial = rawret + (size_t)NR * H;            // GP*7*H
    float* ave     = partial + (size_t)GP * CC * H;      // 7*H
    float* anorm   = ave + (size_t)CC * H;               // 8 (padded)
    unsigned short* ebf = (unsigned short*)(anorm + 8);  // MR*H bf16

    kE<<<(MR * H) / (256 * 8), 256, 0, stream>>>(embeds, ebf);
    kA3<<<NR / 4, 256, 0, stream>>>(embeds, ebf, w_self, w_n, w_n2,
                                    idx, nbr1, nbr2, W1, b1, W2, b2, rawret);
    kC1<<<GP, 256, 0, stream>>>(rawret, labels, partial);
    kC2<<<CC, 256, 0, stream>>>(partial, ave, anorm);
    kD<<<NR / 4, 256, 0, stream>>>(rawret, ave, anorm, out);
}

// Round 4
// 308.695 us; speedup vs baseline: 1.1616x; 1.1616x over previous
//
#include <hip/hip_runtime.h>
#include <hip/hip_bf16.h>
#include <math.h>

#define H 256
#define NR 14000
#define MR 100000
#define K1C 16
#define K2C 32
#define KT 48
#define CC 7
#define EPSF 1e-8f
#define GP 448
#define CH2 32            // GP*CH2 = 14336 >= NR

typedef __attribute__((ext_vector_type(8))) unsigned short ushort8_t;

__device__ __forceinline__ float rdlane(float v, int l) {
    return __int_as_float(__builtin_amdgcn_readlane(__float_as_int(v), l));
}

__device__ __forceinline__ float dot4(const float4 a, const float4 b) {
    return a.x * b.x + a.y * b.y + a.z * b.z + a.w * b.w;
}

__device__ __forceinline__ unsigned short f2bf(float x) {
    __hip_bfloat16 h = __float2bfloat16(x);   // RTNE
    return *(unsigned short*)&h;
}

// ---------------- Kernel E: fp32 table -> bf16 table ------------------------
__global__ __launch_bounds__(256) void kE(const float* __restrict__ src,
                                          unsigned short* __restrict__ dst) {
    const size_t base = ((size_t)blockIdx.x * 256 + threadIdx.x) * 8;
    const float4 a = *(const float4*)(src + base);
    const float4 b = *(const float4*)(src + base + 4);
    ushort8_t o;
    o[0] = f2bf(a.x); o[1] = f2bf(a.y); o[2] = f2bf(a.z); o[3] = f2bf(a.w);
    o[4] = f2bf(b.x); o[5] = f2bf(b.y); o[6] = f2bf(b.z); o[7] = f2bf(b.w);
    *(ushort8_t*)(dst + base) = o;
}

// ---------------- Kernel A4: bf16 gather + cos-softmax, 12-deep prefetch ----
// One wave per n; 4 groups x 16 lanes; lane l owns h in [16l,16l+16).
// ALL 24 gather loads issued before the compute loop (issue order: ridx,
// center+weights, then gathers -> consuming centers only waits vmcnt(24)).
// (256,2) launch bounds authorize ~256 VGPRs so staging stays in registers —
// round-3 lesson: compiler shrinking to 72 VGPRs serialized the gather.
__global__ __launch_bounds__(256, 2) void kA4(
    const float* __restrict__ embeds, const unsigned short* __restrict__ ebf,
    const float* __restrict__ w_self, const float* __restrict__ w_n,
    const float* __restrict__ w_n2, const int* __restrict__ idx,
    const int* __restrict__ nbr1, const int* __restrict__ nbr2,
    float* __restrict__ inbuf, float* __restrict__ cebuf)
{
    const int tid = threadIdx.x;
    const int wv = tid >> 6, lane = tid & 63;
    const int n = blockIdx.x * 4 + wv;
    const int g = lane >> 4, l = lane & 15;
    const int hb = l * 16;

    // --- issue scalar-ish header loads first ---
    const int cidx = idx[n];
    int ridx = 0;
    if (lane < K1C) ridx = nbr1[n * K1C + lane];
    else if (lane < KT) ridx = nbr2[n * K2C + (lane - K1C)];

    const float* crow = embeds + (size_t)cidx * H + hb;
    float4 cv4[4], wsv4[4], wnv4[4], wn2v4[4];
#pragma unroll
    for (int j = 0; j < 4; ++j) {
        cv4[j]   = *(const float4*)(crow + 4 * j);
        wsv4[j]  = *(const float4*)(w_self + hb + 4 * j);
        wnv4[j]  = *(const float4*)(w_n    + hb + 4 * j);
        wn2v4[j] = *(const float4*)(w_n2   + hb + 4 * j);
    }

    // --- all 24 gather loads in flight ---
    int rows[12];
#pragma unroll
    for (int kk = 0; kk < 12; ++kk) rows[kk] = __shfl(ridx, kk * 4 + g);
    ushort8_t pb[24];
#pragma unroll
    for (int kk = 0; kk < 12; ++kk) {
        const unsigned short* rp = ebf + (size_t)rows[kk] * H + hb;
        pb[2 * kk]     = *(const ushort8_t*)(rp);
        pb[2 * kk + 1] = *(const ushort8_t*)(rp + 8);
    }

    // --- center prompt + norm (overlaps with gathers in flight) ---
    float ce[16], wn[16], wn2[16];
    float na2 = 0.f;
#pragma unroll
    for (int j = 0; j < 4; ++j) {
        wn[4*j+0] = wnv4[j].x;  wn[4*j+1] = wnv4[j].y;
        wn[4*j+2] = wnv4[j].z;  wn[4*j+3] = wnv4[j].w;
        wn2[4*j+0] = wn2v4[j].x; wn2[4*j+1] = wn2v4[j].y;
        wn2[4*j+2] = wn2v4[j].z; wn2[4*j+3] = wn2v4[j].w;
        ce[4*j+0] = wsv4[j].x * cv4[j].x; ce[4*j+1] = wsv4[j].y * cv4[j].y;
        ce[4*j+2] = wsv4[j].z * cv4[j].z; ce[4*j+3] = wsv4[j].w * cv4[j].w;
        na2 += ce[4*j+0]*ce[4*j+0] + ce[4*j+1]*ce[4*j+1]
             + ce[4*j+2]*ce[4*j+2] + ce[4*j+3]*ce[4*j+3];
    }
#pragma unroll
    for (int m = 1; m <= 8; m <<= 1) na2 += __shfl_xor(na2, m);
    const float na = fmaxf(sqrtf(na2), EPSF);

    float acc[16];
#pragma unroll
    for (int i = 0; i < 16; ++i) acc[i] = 0.f;
    float lsum = 0.f;

#pragma unroll
    for (int kk = 0; kk < 12; ++kk) {
        const ushort8_t e0 = pb[2 * kk];
        const ushort8_t e1 = pb[2 * kk + 1];
        float nb[16];
#pragma unroll
        for (int i = 0; i < 8; ++i) {
            nb[i]     = __uint_as_float((unsigned)e0[i] << 16);
            nb[8 + i] = __uint_as_float((unsigned)e1[i] << 16);
        }
        float num = 0.f, nn = 0.f;
#pragma unroll
        for (int i = 0; i < 16; ++i) {
            const float w = (kk < 4) ? wn[i] : wn2[i];  // compile-time after unroll
            nb[i] *= w;
            num += ce[i] * nb[i];
            nn  += nb[i] * nb[i];
        }
#pragma unroll
        for (int m = 1; m <= 8; m <<= 1) {
            num += __shfl_xor(num, m);
            nn  += __shfl_xor(nn, m);
        }
        const float nbn = fmaxf(sqrtf(nn), EPSF);
        const float e = __expf(num / (nbn * na) - 1.0f);   // sim <= 1
        lsum += e;
#pragma unroll
        for (int i = 0; i < 16; ++i) acc[i] += e * nb[i];
    }
    // merge the 4 groups (lanes with equal l hold the same h-range)
#pragma unroll
    for (int m = 16; m <= 32; m <<= 1) {
        lsum += __shfl_xor(lsum, m);
#pragma unroll
        for (int i = 0; i < 16; ++i) acc[i] += __shfl_xor(acc[i], m);
    }
    const float rl = 1.0f / lsum;
    if (g == 0) {
        float* ip = inbuf + (size_t)n * H + hb;
        float* cp = cebuf + (size_t)n * H + hb;
#pragma unroll
        for (int i = 0; i < 16; ++i) {
            ip[i] = acc[i] * rl + ce[i];
            cp[i] = ce[i];
        }
    }
}

// ---------------- Kernel B2: adapter rawret = elu(in@W1+b1)@W2 + b2 + ce ----
// (verbatim round-2 version — it was part of the working 243 µs budget)
__global__ __launch_bounds__(256) void kB2(
    float* __restrict__ io, const float* __restrict__ cebuf,
    const float* __restrict__ W1, const float* __restrict__ b1,
    const float* __restrict__ W2, const float* __restrict__ b2)
{
    const int tid = threadIdx.x;
    const int wv = tid >> 6, lane = tid & 63;
    const int r0 = __builtin_amdgcn_readfirstlane((blockIdx.x * 4 + wv) * 4);
    const float* inb = io + (size_t)r0 * H;

    float hid[4];
    const float bb = b1[lane];
#pragma unroll
    for (int r = 0; r < 4; ++r) hid[r] = bb;

#pragma unroll 8
    for (int h = 0; h < 256; ++h) {
        const float w1v = W1[h * 64 + lane];
        hid[0] += inb[h]           * w1v;
        hid[1] += inb[H + h]       * w1v;
        hid[2] += inb[2 * H + h]   * w1v;
        hid[3] += inb[3 * H + h]   * w1v;
    }
#pragma unroll
    for (int r = 0; r < 4; ++r)
        hid[r] = hid[r] > 0.f ? hid[r] : (__expf(hid[r]) - 1.0f);  // elu

    float4 p4[4];
    const float4 b2v = *(const float4*)(b2 + 4 * lane);
#pragma unroll
    for (int r = 0; r < 4; ++r) p4[r] = b2v;
#pragma unroll 4
    for (int b = 0; b < 64; ++b) {
        const float4 w2v = *(const float4*)(W2 + b * H + 4 * lane);
#pragma unroll
        for (int r = 0; r < 4; ++r) {
            const float hv = rdlane(hid[r], b);
            p4[r].x += hv * w2v.x; p4[r].y += hv * w2v.y;
            p4[r].z += hv * w2v.z; p4[r].w += hv * w2v.w;
        }
    }
#pragma unroll
    for (int r = 0; r < 4; ++r) {
        const float4 cev = *(const float4*)(cebuf + (size_t)(r0 + r) * H + 4 * lane);
        float4 ov;
        ov.x = p4[r].x + cev.x; ov.y = p4[r].y + cev.y;
        ov.z = p4[r].z + cev.z; ov.w = p4[r].w + cev.w;
        *(float4*)(io + (size_t)(r0 + r) * H + 4 * lane) = ov;
    }
}

// ---------------- Kernel C1: per-chunk per-class partial sums ---------------
__global__ __launch_bounds__(256) void kC1(
    const float* __restrict__ rawret, const int* __restrict__ labels,
    float* __restrict__ partial)
{
    const int t = threadIdx.x, j = blockIdx.x;
    const int nlo = j * CH2;
    const int nhi = min(nlo + CH2, NR);
    float acc[CC];
#pragma unroll
    for (int c = 0; c < CC; ++c) acc[c] = 0.f;
    for (int n = nlo; n < nhi; n += 4) {      // bounds are multiples of 4
        int lab[4]; float v[4];
#pragma unroll
        for (int u = 0; u < 4; ++u) {
            lab[u] = labels[n + u];
            v[u] = rawret[(size_t)(n + u) * H + t];
        }
#pragma unroll
        for (int u = 0; u < 4; ++u)
#pragma unroll
            for (int c = 0; c < CC; ++c) acc[c] += (lab[u] == c) ? v[u] : 0.f;
    }
#pragma unroll
    for (int c = 0; c < CC; ++c) partial[(size_t)(j * CC + c) * H + t] = acc[c];
}

// ---------------- Kernel C2: finalize class means (56 blocks) ---------------
// block b: class c = b>>3, h-slice s = b&7. 256 threads = 32 h x 8 j-groups.
__global__ __launch_bounds__(256) void kC2(
    const float* __restrict__ partial, float* __restrict__ ave)
{
    const int b = blockIdx.x, c = b >> 3, s = b & 7;
    const int hloc = threadIdx.x & 31, jg = threadIdx.x >> 5;
    const int h = 32 * s + hloc;
    float sum = 0.f;
#pragma unroll 8
    for (int j = jg; j < GP; j += 8)
        sum += partial[(size_t)(j * CC + c) * H + h];
    __shared__ float red[256];
    red[threadIdx.x] = sum;
    __syncthreads();
    if (jg == 0) {
#pragma unroll
        for (int t = 1; t < 8; ++t) sum += red[t * 32 + hloc];
        ave[c * H + h] = sum * (1.0f / 2000.0f);   // per_class = N // C
    }
}

// ---------------- Kernel D2: class-cosine softmax (anorm inline) ------------
__global__ __launch_bounds__(256) void kD2(
    const float* __restrict__ rawret, const float* __restrict__ ave,
    float* __restrict__ out)
{
    const int tid = threadIdx.x;
    const int wv = tid >> 6, lane = tid & 63;
    const int n = blockIdx.x * 4 + wv;
    const float4 r4 = *(const float4*)(rawret + (size_t)n * H + 4 * lane);
    float nr2 = dot4(r4, r4);
#pragma unroll
    for (int m = 1; m <= 32; m <<= 1) nr2 += __shfl_xor(nr2, m);
    const float rn = fmaxf(sqrtf(nr2), EPSF);

    float e[CC];
    float s = 0.f;
#pragma unroll
    for (int c = 0; c < CC; ++c) {
        const float4 a4 = *(const float4*)(ave + c * H + 4 * lane);
        float d = dot4(r4, a4);
        float an = dot4(a4, a4);
#pragma unroll
        for (int m = 1; m <= 32; m <<= 1) {
            d  += __shfl_xor(d, m);
            an += __shfl_xor(an, m);
        }
        const float anorm = fmaxf(sqrtf(an), EPSF);
        const float sim = d / (rn * anorm);
        e[c] = __expf(sim - 1.0f);   // |sim| <= 1, fixed-shift softmax
        s += e[c];
    }
    const float rs = 1.0f / s;
    if (lane < CC) {
        float v = e[0];
#pragma unroll
        for (int c = 1; c < CC; ++c) v = (lane == c) ? e[c] : v;
        out[(size_t)n * CC + lane] = v * rs;
    }
}

extern "C" void kernel_launch(void* const* d_in, const int* in_sizes, int n_in,
                              void* d_out, int out_size, void* d_ws, size_t ws_size,
                              hipStream_t stream) {
    const float* embeds = (const float*)d_in[0];
    const float* w_self = (const float*)d_in[1];
    const float* w_n    = (const float*)d_in[2];
    const float* w_n2   = (const float*)d_in[3];
    const float* W1     = (const float*)d_in[4];
    const float* b1     = (const float*)d_in[5];
    const float* W2     = (const float*)d_in[6];
    const float* b2     = (const float*)d_in[7];
    const int* idx      = (const int*)d_in[8];
    const int* nbr1     = (const int*)d_in[9];
    const int* nbr2     = (const int*)d_in[10];
    const int* labels   = (const int*)d_in[11];
    float* out = (float*)d_out;

    float* rawret  = (float*)d_ws;                       // N*H (inputs->rawret)
    float* cebuf   = rawret + (size_t)NR * H;            // N*H
    float* partial = cebuf + (size_t)NR * H;             // GP*7*H
    float* ave     = partial + (size_t)GP * CC * H;      // 7*H
    unsigned short* ebf = (unsigned short*)(ave + CC * H + 8);  // MR*H bf16

    kE<<<(MR * H) / (256 * 8), 256, 0, stream>>>(embeds, ebf);
    kA4<<<NR / 4, 256, 0, stream>>>(embeds, ebf, w_self, w_n, w_n2,
                                    idx, nbr1, nbr2, rawret, cebuf);
    kB2<<<NR / 16, 256, 0, stream>>>(rawret, cebuf, W1, b1, W2, b2);
    kC1<<<GP, 256, 0, stream>>>(rawret, labels, partial);
    kC2<<<56, 256, 0, stream>>>(partial, ave);
    kD2<<<NR / 4, 256, 0, stream>>>(rawret, ave, out);
}